// Round 17
// baseline (109.073 us; speedup 1.0000x reference)
//
#include <hip/hip_runtime.h>
#include <stdint.h>

#define VSZ 30000
#define TPS 2048      // trees per side
#define G3  384

// workspace layout (float offsets)
#define OFF_PROJ   0u          // 30000*128 bf16 = 1,920,000 floats
#define OFF_SEQ    1920000u    // 2*2048*128
#define OFF_HFIN   2444288u    // 256*128
#define OFF_FRAG   2477056u    // 24576 uint4 = 98304 floats

using f32x4 = __attribute__((ext_vector_type(4))) float;
using s16x8 = __attribute__((ext_vector_type(8))) short;
union U8 { uint4 u; s16x8 s; };

__device__ __forceinline__ float sigm(float x) { return 1.0f / (1.0f + __expf(-x)); }
__device__ __forceinline__ float tanh_fast(float x) {
  float e = __expf(-2.0f * x);
  return 2.0f / (1.0f + e) - 1.0f;   // safe at both tails (no inf/inf)
}
__device__ __forceinline__ unsigned bf16_rn(float f) {
  unsigned u = __float_as_uint(f);
  return (u + 0x7FFFu + ((u >> 16) & 1u)) >> 16;   // round-to-nearest-even
}

#define KT 1040     // bytes per ktile (64 lanes * 16B + 16B pad)
#define XS 4160     // bytes per 16-row B-tile (4 ktiles)
#define MM(dst, A, B) dst = __builtin_amdgcn_mfma_f32_16x16x32_bf16(A, B, dst, 0, 0, 0)

// ---- K0: pre-pack GRU weight MFMA A-fragments as bf16, one dwordx4/lane.
//      idx = ((((dir*8+w)*2+mat)*3+g)*4+t)*64 + l   (mat0=W_ih, mat1=W_hh)
__global__ __launch_bounds__(256) void k_pack(
    const float* __restrict__ w_ih_f, const float* __restrict__ w_ih_b,
    const float* __restrict__ w_hh_f, const float* __restrict__ w_hh_b,
    uint4* __restrict__ fragimg) {
  int idx = blockIdx.x * 256 + threadIdx.x;    // 0..24575
  int l = idx & 63;
  int t = (idx >> 6) & 3;
  int r = idx >> 8;
  int g = r % 3; r /= 3;
  int mat = r & 1; r >>= 1;
  int w = r & 7;
  int dir = r >> 3;
  const float* src = mat ? (dir ? w_hh_b : w_hh_f) : (dir ? w_ih_b : w_ih_f);
  int row = g * 128 + 16 * w + (l & 15);
  int ks  = t * 32 + (l >> 4) * 8;
  float4 f0 = *(const float4*)&src[row * 128 + ks];
  float4 f1 = *(const float4*)&src[row * 128 + ks + 4];
  uint4 u;
  u.x = bf16_rn(f0.x) | (bf16_rn(f0.y) << 16);
  u.y = bf16_rn(f0.z) | (bf16_rn(f0.w) << 16);
  u.z = bf16_rn(f1.x) | (bf16_rn(f1.y) << 16);
  u.w = bf16_rn(f1.z) | (bf16_rn(f1.w) << 16);
  fragimg[idx] = u;
}

// ---- K1: MFMA vocab projection (verified round 12).
__global__ __launch_bounds__(512) void k_proj(const float* __restrict__ emb,
                                              const float* __restrict__ w_c,
                                              const float* __restrict__ b_c,
                                              unsigned short* __restrict__ projb) {
  __shared__ __align__(16) char blds[8 * XS];   // 33280 B
  int tid = threadIdx.x;
  int v0 = blockIdx.x * 128;
  {
    int pp = tid >> 5, cc = tid & 31;
    int wbyte = (cc >> 3) * KT + (pp + 16 * ((cc & 7) >> 1)) * 16 + (cc & 1) * 8;
    for (int nt = 0; nt < 8; ++nt) {
      int row = v0 + nt * 16 + pp;
      float4 v = make_float4(0.f, 0.f, 0.f, 0.f);
      if (row < VSZ) v = *(const float4*)&emb[(size_t)row * 128 + 4 * cc];
      uint2 u;
      u.x = bf16_rn(v.x) | (bf16_rn(v.y) << 16);
      u.y = bf16_rn(v.z) | (bf16_rn(v.w) << 16);
      *(uint2*)(blds + nt * XS + wbyte) = u;
    }
  }
  int w = tid >> 6, l = tid & 63;
  s16x8 af[4];
  {
    int row = 16 * w + (l & 15);
    int kb = (l >> 4) * 8;
#pragma unroll
    for (int t = 0; t < 4; ++t) {
      float4 f0 = *(const float4*)&w_c[row * 128 + t * 32 + kb];
      float4 f1 = *(const float4*)&w_c[row * 128 + t * 32 + kb + 4];
      U8 u;
      u.u.x = bf16_rn(f0.x) | (bf16_rn(f0.y) << 16);
      u.u.y = bf16_rn(f0.z) | (bf16_rn(f0.w) << 16);
      u.u.z = bf16_rn(f1.x) | (bf16_rn(f1.y) << 16);
      u.u.w = bf16_rn(f1.z) | (bf16_rn(f1.w) << 16);
      af[t] = u.s;
    }
  }
  f32x4 bias = *(const f32x4*)&b_c[16 * w + (l >> 4) * 4];
  __syncthreads();
  for (int nt = 0; nt < 8; ++nt) {
    s16x8 bf[4];
#pragma unroll
    for (int t = 0; t < 4; ++t) {
      U8 u; u.u = *(const uint4*)(blds + nt * XS + t * KT + l * 16);
      bf[t] = u.s;
    }
    f32x4 acc = bias;
    MM(acc, af[0], bf[0]); MM(acc, af[1], bf[1]);
    MM(acc, af[2], bf[2]); MM(acc, af[3], bf[3]);
    int v = v0 + nt * 16 + (l & 15);
    if (v < VSZ) {
      uint2 u;
      u.x = bf16_rn(acc[0]) | (bf16_rn(acc[1]) << 16);
      u.y = bf16_rn(acc[2]) | (bf16_rn(acc[3]) << 16);
      *(uint2*)&projb[(size_t)v * 128 + 16 * w + (l >> 4) * 4] = u;
    }
  }
}

// ---- K2: per-tree subtree sums (heap), coord-wise max, ReLU -> seq[side][t][c]
__global__ __launch_bounds__(512) void k_tree(const int* __restrict__ tokens1,
                                              const int* __restrict__ tokens2,
                                              const unsigned short* __restrict__ projb,
                                              float* __restrict__ seq) {
  __shared__ int tok[4][64];
  int side = blockIdx.y;
  const int* tokens = side ? tokens2 : tokens1;
  int t0 = blockIdx.x * 4;
  if (threadIdx.x < 256) {
    int tl = threadIdx.x >> 6, j = threadIdx.x & 63;
    tok[tl][j] = tokens[(t0 + tl) * 64 + j];
  }
  __syncthreads();
  int tl = threadIdx.x >> 7;
  int c  = threadIdx.x & 127;
  float s[64];
#pragma unroll
  for (int j = 0; j < 64; ++j)
    s[j] = __uint_as_float(((unsigned)projb[(size_t)tok[tl][j] * 128 + c]) << 16);
  s[31] += s[63];
#pragma unroll
  for (int j = 30; j >= 0; --j) s[j] += s[2 * j + 1] + s[2 * j + 2];
  float m = s[0];
#pragma unroll
  for (int j = 1; j < 64; ++j) m = fmaxf(m, s[j]);
  m = fmaxf(m, 0.0f);
  seq[(size_t)(side * TPS + t0 + tl) * 128 + c] = m;
}

// ---- K3: fused GRU scans via MFMA, phase-overlapped:
//      W_hh in LDS (98KB) + x chunks (33KB) + h dbuf (8KB);
//      W_ih streams from L2 but the 12 fragment loads for step i+1 are
//      ISSUED mid-step-i through a laundered pointer (defeats LICM/remat
//      placement) and stay in flight across the raw lgkmcnt-only barrier
//      (T3/T4) -- the L2 phase now overlaps the LDS+VALU phases instead of
//      serializing in front of them (r16: serial, 3670 cyc/step).
__global__ __launch_bounds__(512, 2) void k_scan(
    const float* __restrict__ seq,
    const uint4* __restrict__ fragimg,
    const float* __restrict__ b_ih_f, const float* __restrict__ b_ih_b,
    const float* __restrict__ b_hh_f, const float* __restrict__ b_hh_b,
    float* __restrict__ hfin) {
  __shared__ __align__(16) uint4 wlds[6144];        // 98304 B: W_hh frags
  __shared__ __align__(16) char  xlds[8 * XS];      // 33280 B: 8-step x chunk
  __shared__ __align__(16) unsigned hbuf[2][1040];  // 8320 B: h dbuf
  int bx = blockIdx.x;
  int sd = bx & 3, pg = bx >> 2;
  int side = sd >> 1, dir = sd & 1;
  const float* bih = dir ? b_ih_b : b_ih_f;
  const float* bhh = dir ? b_hh_b : b_hh_f;
  int tid = threadIdx.x;
  int w = tid >> 6, l = tid & 63;
  int p  = l & 15;          // program (B n / D col)
  int kb = l >> 4;          // k-block within fragment
  int c0 = 16 * w + 4 * kb; // D-row base

  // stage W_hh fragments (mat=1 section of fragimg) -> LDS  [r13 verified]
  for (int i = tid; i < 6144; i += 512) {
    int w_ = i / 768, r = i - w_ * 768;
    wlds[i] = fragimg[(size_t)(dir * 8 + w_) * 1536 + 768 + r];
  }
  for (int i = tid; i < 2080; i += 512) ((unsigned*)hbuf)[i] = 0u;

  // x staging geometry (r12/r16 verified)
  int pp = tid >> 5, cc = tid & 31;
  int xwb = (cc >> 3) * KT + (pp + 16 * ((cc & 7) >> 1)) * 16 + (cc & 1) * 8;
  const float* srow = seq + (size_t)(side * TPS + (pg * 16 + pp) * 32) * 128 + 4 * cc;
#pragma unroll
  for (int ss = 0; ss < 8; ++ss) {
    int pos = dir ? (31 - ss) : ss;
    float4 v = *(const float4*)(srow + (size_t)pos * 128);
    uint2 u;
    u.x = bf16_rn(v.x) | (bf16_rn(v.y) << 16);
    u.y = bf16_rn(v.z) | (bf16_rn(v.w) << 16);
    *(uint2*)(xlds + ss * XS + xwb) = u;
  }

  // W_ih A-fragments: initial fill (direct b128 loads into s16x8)
  const uint4* fbase = fragimg + (size_t)(dir * 8 + w) * 1536 + l;
  s16x8 aiP[3][4];
#pragma unroll
  for (int g = 0; g < 3; ++g)
#pragma unroll
    for (int t = 0; t < 4; ++t)
      aiP[g][t] = *(const s16x8*)&fbase[g * 256 + t * 64];

  f32x4 bir = *(const f32x4*)&bih[c0],       bhr = *(const f32x4*)&bhh[c0];
  f32x4 biz = *(const f32x4*)&bih[128 + c0], bhz = *(const f32x4*)&bhh[128 + c0];
  f32x4 bin = *(const f32x4*)&bih[256 + c0], bhn = *(const f32x4*)&bhh[256 + c0];
  f32x4 bbr = bir + bhr, bbz = biz + bhz;

  int hwb = (c0 >> 5) * KT + (p + 16 * ((c0 & 31) >> 3)) * 16 + (c0 & 7) * 2;
  const uint4* wbase = wlds + w * 768 + l;   // + (g*4+t)*64

  float hc[4] = {0.f, 0.f, 0.f, 0.f};
  f32x4 z4 = {0.f, 0.f, 0.f, 0.f};
  __syncthreads();   // W_hh + hbuf + chunk0 visible

  for (int i = 0; i < 32; ++i) {
    if (i && (i & 7) == 0) {
      // re-stage x chunk for steps i..i+7 (prior chunk fully consumed --
      // all reads drained by the lgkmcnt(0) before the last barrier)
#pragma unroll
      for (int ss = 0; ss < 8; ++ss) {
        int pos = dir ? (31 - (i + ss)) : (i + ss);
        float4 v = *(const float4*)(srow + (size_t)pos * 128);
        uint2 u;
        u.x = bf16_rn(v.x) | (bf16_rn(v.y) << 16);
        u.y = bf16_rn(v.z) | (bf16_rn(v.w) << 16);
        *(uint2*)(xlds + ss * XS + xwb) = u;
      }
      asm volatile("s_waitcnt lgkmcnt(0)" ::: "memory");
      __builtin_amdgcn_s_barrier();
      __builtin_amdgcn_sched_barrier(0);
    }
    const char* xb = xlds + (i & 7) * XS;
    const char* hb = (const char*)hbuf + (i & 1) * 4160;
    s16x8 xf[4], bf[4];
#pragma unroll
    for (int t = 0; t < 4; ++t) {
      xf[t] = *(const s16x8*)(xb + t * KT + l * 16);
      bf[t] = *(const s16x8*)(hb + t * KT + l * 16);
    }
    f32x4 aR0 = bbr, aR1 = z4, aZ0 = bbz, aZ1 = z4;
    f32x4 aNi0 = bin, aNi1 = z4, aNh0 = bhn, aNh1 = z4;
    // x-part: consumes aiP (loads issued last step, vmcnt waited here)
    MM(aR0,  aiP[0][0], xf[0]); MM(aZ0,  aiP[1][0], xf[0]); MM(aNi0, aiP[2][0], xf[0]);
    MM(aR1,  aiP[0][1], xf[1]); MM(aZ1,  aiP[1][1], xf[1]); MM(aNi1, aiP[2][1], xf[1]);
    MM(aR0,  aiP[0][2], xf[2]); MM(aZ0,  aiP[1][2], xf[2]); MM(aNi0, aiP[2][2], xf[2]);
    MM(aR1,  aiP[0][3], xf[3]); MM(aZ1,  aiP[1][3], xf[3]); MM(aNi1, aiP[2][3], xf[3]);
    // refill aiP for next step NOW; laundered pointer defeats LICM so the
    // loads issue here and stay in flight across the raw barrier. Values are
    // loop-invariant -> correct under any scheduling.
    {
      const uint4* fb = fbase;
      asm volatile("" : "+v"(fb));
#pragma unroll
      for (int g = 0; g < 3; ++g)
#pragma unroll
        for (int t = 0; t < 4; ++t)
          aiP[g][t] = *(const s16x8*)&fb[g * 256 + t * 64];
    }
    // h-part: W_hh from LDS
#pragma unroll
    for (int t = 0; t < 4; ++t) {
      s16x8 u0 = *(const s16x8*)&wbase[t * 64];
      s16x8 u1 = *(const s16x8*)&wbase[(4 + t) * 64];
      s16x8 u2 = *(const s16x8*)&wbase[(8 + t) * 64];
      if (t & 1) { MM(aR1, u0, bf[t]); MM(aZ1, u1, bf[t]); MM(aNh1, u2, bf[t]); }
      else       { MM(aR0, u0, bf[t]); MM(aZ0, u1, bf[t]); MM(aNh0, u2, bf[t]); }
    }
#pragma unroll
    for (int r4 = 0; r4 < 4; ++r4) {
      float rv = sigm(aR0[r4] + aR1[r4]);
      float zv = sigm(aZ0[r4] + aZ1[r4]);
      float nv = tanh_fast(aNi0[r4] + aNi1[r4] + rv * (aNh0[r4] + aNh1[r4]));
      hc[r4] = (1.0f - zv) * nv + zv * hc[r4];
    }
    // h-pack via HW packed convert (T12 recipe; RNE like bf16_rn)
    unsigned hp0, hp1;
    asm("v_cvt_pk_bf16_f32 %0, %1, %2" : "=v"(hp0) : "v"(hc[0]), "v"(hc[1]));
    asm("v_cvt_pk_bf16_f32 %0, %1, %2" : "=v"(hp1) : "v"(hc[2]), "v"(hc[3]));
    uint2 hp; hp.x = hp0; hp.y = hp1;
    *(uint2*)((char*)hbuf + ((i + 1) & 1) * 4160 + hwb) = hp;
    // raw barrier: drain LDS only; W_ih prefetch stays in flight
    asm volatile("s_waitcnt lgkmcnt(0)" ::: "memory");
    __builtin_amdgcn_s_barrier();
    __builtin_amdgcn_sched_barrier(0);
  }
  int scan = sd * 64 + pg * 16 + p;
#pragma unroll
  for (int r4 = 0; r4 < 4; ++r4)
    hfin[(size_t)scan * 128 + c0 + r4] = hc[r4];
}

// ---- K4: out[b] = sigmoid(|lvec-rvec| . w_out + b_out)
__global__ __launch_bounds__(64) void k_out(const float* __restrict__ hfin,
                                            const float* __restrict__ w_out,
                                            const float* __restrict__ b_out,
                                            float* __restrict__ out) {
  int b = blockIdx.x, lane = threadIdx.x;
  float p = 0.f;
#pragma unroll
  for (int i = 0; i < 2; ++i) {
    int c = lane + i * 64;
    float l = hfin[(size_t)(0   + b) * 128 + c] + hfin[(size_t)(64  + b) * 128 + c];
    float r = hfin[(size_t)(128 + b) * 128 + c] + hfin[(size_t)(192 + b) * 128 + c];
    p += fabsf(l - r) * w_out[c];
  }
#pragma unroll
  for (int off = 32; off > 0; off >>= 1) p += __shfl_down(p, off);
  if (lane == 0) out[b] = sigm(p + b_out[0]);
}

extern "C" void kernel_launch(void* const* d_in, const int* in_sizes, int n_in,
                              void* d_out, int out_size, void* d_ws, size_t ws_size,
                              hipStream_t stream) {
  (void)in_sizes; (void)n_in; (void)out_size; (void)ws_size;
  const int*   tokens1 = (const int*)d_in[0];
  const int*   tokens2 = (const int*)d_in[2];
  const float* emb     = (const float*)d_in[4];
  const float* w_c     = (const float*)d_in[5];
  const float* b_c     = (const float*)d_in[6];
  const float* w_ih_f  = (const float*)d_in[7];
  const float* w_hh_f  = (const float*)d_in[8];
  const float* b_ih_f  = (const float*)d_in[9];
  const float* b_hh_f  = (const float*)d_in[10];
  const float* w_ih_b  = (const float*)d_in[11];
  const float* w_hh_b  = (const float*)d_in[12];
  const float* b_ih_b  = (const float*)d_in[13];
  const float* b_hh_b  = (const float*)d_in[14];
  const float* w_out   = (const float*)d_in[15];
  const float* b_out   = (const float*)d_in[16];
  float* ws = (float*)d_ws;
  unsigned short* projb = (unsigned short*)(ws + OFF_PROJ);
  float* seq    = ws + OFF_SEQ;
  float* hfin   = ws + OFF_HFIN;
  uint4* fragimg = (uint4*)(ws + OFF_FRAG);

  k_pack<<<96, 256, 0, stream>>>(w_ih_f, w_ih_b, w_hh_f, w_hh_b, fragimg);
  k_proj<<<(VSZ + 127) / 128, 512, 0, stream>>>(emb, w_c, b_c, projb);
  k_tree<<<dim3(TPS / 4, 2), 512, 0, stream>>>(tokens1, tokens2, projb, seq);
  k_scan<<<16, 512, 0, stream>>>(seq, fragimg, b_ih_f, b_ih_b, b_hh_f, b_hh_b, hfin);
  k_out<<<64, 64, 0, stream>>>(hfin, w_out, b_out, (float*)d_out);
}

// Round 19
// 96.022 us; speedup vs baseline: 1.1359x; 1.1359x over previous
//
#include <hip/hip_runtime.h>
#include <stdint.h>

#define VSZ 30000
#define TPS 2048      // trees per side
#define G3  384

// workspace layout (float offsets)
#define OFF_PROJ   0u          // 30000*128 bf16 = 1,920,000 floats
#define OFF_SEQ    1920000u    // 2*2048*128
#define OFF_HFIN   2444288u    // 256*128
#define OFF_FRAG   2477056u    // 24576 uint4 = 98304 floats

using f32x4 = __attribute__((ext_vector_type(4))) float;
using s16x8 = __attribute__((ext_vector_type(8))) short;
union U8 { uint4 u; s16x8 s; };

__device__ __forceinline__ float sigm(float x) { return 1.0f / (1.0f + __expf(-x)); }
__device__ __forceinline__ float tanh_fast(float x) {
  float e = __expf(-2.0f * x);
  return 2.0f / (1.0f + e) - 1.0f;   // safe at both tails (no inf/inf)
}
__device__ __forceinline__ unsigned bf16_rn(float f) {
  unsigned u = __float_as_uint(f);
  return (u + 0x7FFFu + ((u >> 16) & 1u)) >> 16;   // round-to-nearest-even
}

#define KT 1040     // bytes per ktile (64 lanes * 16B + 16B pad)
#define XS 4160     // bytes per 16-row B-tile (4 ktiles)
#define MM(dst, A, B) dst = __builtin_amdgcn_mfma_f32_16x16x32_bf16(A, B, dst, 0, 0, 0)

// ---- K0: pre-pack GRU weight MFMA A-fragments as bf16, one dwordx4/lane.
//      idx = ((((dir*8+w)*2+mat)*3+g)*4+t)*64 + l   (mat0=W_ih, mat1=W_hh)
__global__ __launch_bounds__(256) void k_pack(
    const float* __restrict__ w_ih_f, const float* __restrict__ w_ih_b,
    const float* __restrict__ w_hh_f, const float* __restrict__ w_hh_b,
    uint4* __restrict__ fragimg) {
  int idx = blockIdx.x * 256 + threadIdx.x;    // 0..24575
  int l = idx & 63;
  int t = (idx >> 6) & 3;
  int r = idx >> 8;
  int g = r % 3; r /= 3;
  int mat = r & 1; r >>= 1;
  int w = r & 7;
  int dir = r >> 3;
  const float* src = mat ? (dir ? w_hh_b : w_hh_f) : (dir ? w_ih_b : w_ih_f);
  int row = g * 128 + 16 * w + (l & 15);
  int ks  = t * 32 + (l >> 4) * 8;
  float4 f0 = *(const float4*)&src[row * 128 + ks];
  float4 f1 = *(const float4*)&src[row * 128 + ks + 4];
  uint4 u;
  u.x = bf16_rn(f0.x) | (bf16_rn(f0.y) << 16);
  u.y = bf16_rn(f0.z) | (bf16_rn(f0.w) << 16);
  u.z = bf16_rn(f1.x) | (bf16_rn(f1.y) << 16);
  u.w = bf16_rn(f1.z) | (bf16_rn(f1.w) << 16);
  fragimg[idx] = u;
}

// ---- K1: MFMA vocab projection. proj[v][eo] = b_c[eo] + emb[v][:].w_c[eo][:]
__global__ __launch_bounds__(512) void k_proj(const float* __restrict__ emb,
                                              const float* __restrict__ w_c,
                                              const float* __restrict__ b_c,
                                              unsigned short* __restrict__ projb) {
  __shared__ __align__(16) char blds[8 * XS];   // 33280 B
  int tid = threadIdx.x;
  int v0 = blockIdx.x * 128;
  {
    int pp = tid >> 5, cc = tid & 31;
    int wbyte = (cc >> 3) * KT + (pp + 16 * ((cc & 7) >> 1)) * 16 + (cc & 1) * 8;
    for (int nt = 0; nt < 8; ++nt) {
      int row = v0 + nt * 16 + pp;
      float4 v = make_float4(0.f, 0.f, 0.f, 0.f);
      if (row < VSZ) v = *(const float4*)&emb[(size_t)row * 128 + 4 * cc];
      uint2 u;
      u.x = bf16_rn(v.x) | (bf16_rn(v.y) << 16);
      u.y = bf16_rn(v.z) | (bf16_rn(v.w) << 16);
      *(uint2*)(blds + nt * XS + wbyte) = u;
    }
  }
  int w = tid >> 6, l = tid & 63;
  s16x8 af[4];
  {
    int row = 16 * w + (l & 15);
    int kb = (l >> 4) * 8;
#pragma unroll
    for (int t = 0; t < 4; ++t) {
      float4 f0 = *(const float4*)&w_c[row * 128 + t * 32 + kb];
      float4 f1 = *(const float4*)&w_c[row * 128 + t * 32 + kb + 4];
      U8 u;
      u.u.x = bf16_rn(f0.x) | (bf16_rn(f0.y) << 16);
      u.u.y = bf16_rn(f0.z) | (bf16_rn(f0.w) << 16);
      u.u.z = bf16_rn(f1.x) | (bf16_rn(f1.y) << 16);
      u.u.w = bf16_rn(f1.z) | (bf16_rn(f1.w) << 16);
      af[t] = u.s;
    }
  }
  f32x4 bias = *(const f32x4*)&b_c[16 * w + (l >> 4) * 4];
  __syncthreads();
  for (int nt = 0; nt < 8; ++nt) {
    s16x8 bf[4];
#pragma unroll
    for (int t = 0; t < 4; ++t) {
      U8 u; u.u = *(const uint4*)(blds + nt * XS + t * KT + l * 16);
      bf[t] = u.s;
    }
    f32x4 acc = bias;
    MM(acc, af[0], bf[0]); MM(acc, af[1], bf[1]);
    MM(acc, af[2], bf[2]); MM(acc, af[3], bf[3]);
    int v = v0 + nt * 16 + (l & 15);
    if (v < VSZ) {
      uint2 u;
      u.x = bf16_rn(acc[0]) | (bf16_rn(acc[1]) << 16);
      u.y = bf16_rn(acc[2]) | (bf16_rn(acc[3]) << 16);
      *(uint2*)&projb[(size_t)v * 128 + 16 * w + (l >> 4) * 4] = u;
    }
  }
}

// ---- K2: per-tree subtree sums (heap), coord-wise max, ReLU -> seq[side][t][c]
__global__ __launch_bounds__(512) void k_tree(const int* __restrict__ tokens1,
                                              const int* __restrict__ tokens2,
                                              const unsigned short* __restrict__ projb,
                                              float* __restrict__ seq) {
  __shared__ int tok[4][64];
  int side = blockIdx.y;
  const int* tokens = side ? tokens2 : tokens1;
  int t0 = blockIdx.x * 4;
  if (threadIdx.x < 256) {
    int tl = threadIdx.x >> 6, j = threadIdx.x & 63;
    tok[tl][j] = tokens[(t0 + tl) * 64 + j];
  }
  __syncthreads();
  int tl = threadIdx.x >> 7;
  int c  = threadIdx.x & 127;
  float s[64];
#pragma unroll
  for (int j = 0; j < 64; ++j)
    s[j] = __uint_as_float(((unsigned)projb[(size_t)tok[tl][j] * 128 + c]) << 16);
  s[31] += s[63];
#pragma unroll
  for (int j = 30; j >= 0; --j) s[j] += s[2 * j + 1] + s[2 * j + 2];
  float m = s[0];
#pragma unroll
  for (int j = 1; j < 64; ++j) m = fmaxf(m, s[j]);
  m = fmaxf(m, 0.0f);
  seq[(size_t)(side * TPS + t0 + tl) * 128 + c] = m;
}

// ---- K3: fused GRU scans via MFMA (round-10/12 form, verified best total).
//      x staged bf16 in LDS; weight fragments = single dwordx4 loads from
//      fragimg (allocator worst case = cheap L2 reloads, no convert DAG).
__global__ __launch_bounds__(512) void k_scan(
    const float* __restrict__ seq,
    const uint4* __restrict__ fragimg,
    const float* __restrict__ b_ih_f, const float* __restrict__ b_ih_b,
    const float* __restrict__ b_hh_f, const float* __restrict__ b_hh_b,
    float* __restrict__ hfin) {
  __shared__ __align__(16) unsigned lds[35360];   // 141440 B: 32 x-tiles + 2 h-tiles
  int bx = blockIdx.x;
  int sd = bx & 3, pg = bx >> 2;
  int side = sd >> 1, dir = sd & 1;
  const float* bih = dir ? b_ih_b : b_ih_f;
  const float* bhh = dir ? b_hh_b : b_hh_f;
  int tid = threadIdx.x;
  int w = tid >> 6, l = tid & 63;
  int p  = l & 15;          // program (B n / D col)
  int kb = l >> 4;          // k-block within fragment
  int c0 = 16 * w + 4 * kb; // D-row base

  // --- stage x -> LDS bf16 B-frag tiles (by sequence position)
  {
    int pp = tid >> 5, cc = tid & 31;
    int wbyte = (cc >> 3) * KT + (pp + 16 * ((cc & 7) >> 1)) * 16 + (cc & 1) * 8;
    const float* srow = seq + (size_t)(side * TPS + (pg * 16 + pp) * 32) * 128 + 4 * cc;
    for (int ss = 0; ss < 32; ++ss) {
      float4 v = *(const float4*)(srow + (size_t)ss * 128);
      uint2 u;
      u.x = bf16_rn(v.x) | (bf16_rn(v.y) << 16);
      u.y = bf16_rn(v.z) | (bf16_rn(v.w) << 16);
      *(uint2*)((char*)lds + ss * XS + wbyte) = u;
    }
  }
  for (int i = tid; i < 2080; i += 512) lds[32 * 1040 + i] = 0u;

  // --- persistent A-fragments: single 16B load each from fragimg
  const uint4* fbase = fragimg + (size_t)(dir * 8 + w) * 1536 + l;
  s16x8 ai[3][4], ah[3][4];
#pragma unroll
  for (int g = 0; g < 3; ++g)
#pragma unroll
    for (int t = 0; t < 4; ++t) {
      U8 u;
      u.u = fbase[g * 256 + t * 64];        ai[g][t] = u.s;   // W_ih
      u.u = fbase[768 + g * 256 + t * 64];  ah[g][t] = u.s;   // W_hh
    }

  f32x4 bir = *(const f32x4*)&bih[c0],       bhr = *(const f32x4*)&bhh[c0];
  f32x4 biz = *(const f32x4*)&bih[128 + c0], bhz = *(const f32x4*)&bhh[128 + c0];
  f32x4 bin = *(const f32x4*)&bih[256 + c0], bhn = *(const f32x4*)&bhh[256 + c0];
  f32x4 bbr = bir + bhr, bbz = biz + bhz;

  int hwb = (c0 >> 5) * KT + (p + 16 * ((c0 & 31) >> 3)) * 16 + (c0 & 7) * 2;

  float hc[4] = {0.f, 0.f, 0.f, 0.f};
  f32x4 z4 = {0.f, 0.f, 0.f, 0.f};
  __syncthreads();

  for (int i = 0; i < 32; ++i) {
    int pos = dir ? (31 - i) : i;
    const char* xb = (const char*)lds + pos * XS;
    const char* hb = (const char*)lds + (32 + (i & 1)) * XS;
    s16x8 xf[4], bf[4];
#pragma unroll
    for (int t = 0; t < 4; ++t) {
      U8 ux; ux.u = *(const uint4*)(xb + t * KT + l * 16); xf[t] = ux.s;
      U8 uh; uh.u = *(const uint4*)(hb + t * KT + l * 16); bf[t] = uh.s;
    }
    f32x4 aR0 = bbr, aR1 = z4, aZ0 = bbz, aZ1 = z4;
    f32x4 aNi0 = bin, aNi1 = z4, aNh0 = bhn, aNh1 = z4;
    MM(aR0,  ai[0][0], xf[0]); MM(aZ0,  ai[1][0], xf[0]); MM(aNi0, ai[2][0], xf[0]);
    MM(aR1,  ai[0][1], xf[1]); MM(aZ1,  ai[1][1], xf[1]); MM(aNi1, ai[2][1], xf[1]);
    MM(aR0,  ai[0][2], xf[2]); MM(aZ0,  ai[1][2], xf[2]); MM(aNi0, ai[2][2], xf[2]);
    MM(aR1,  ai[0][3], xf[3]); MM(aZ1,  ai[1][3], xf[3]); MM(aNi1, ai[2][3], xf[3]);
    MM(aNh0, ah[2][0], bf[0]); MM(aR0,  ah[0][0], bf[0]); MM(aZ0,  ah[1][0], bf[0]);
    MM(aNh1, ah[2][1], bf[1]); MM(aR1,  ah[0][1], bf[1]); MM(aZ1,  ah[1][1], bf[1]);
    MM(aNh0, ah[2][2], bf[2]); MM(aR0,  ah[0][2], bf[2]); MM(aZ0,  ah[1][2], bf[2]);
    MM(aNh1, ah[2][3], bf[3]); MM(aR1,  ah[0][3], bf[3]); MM(aZ1,  ah[1][3], bf[3]);
#pragma unroll
    for (int r4 = 0; r4 < 4; ++r4) {
      float rv = sigm(aR0[r4] + aR1[r4]);
      float zv = sigm(aZ0[r4] + aZ1[r4]);
      float nv = tanh_fast(aNi0[r4] + aNi1[r4] + rv * (aNh0[r4] + aNh1[r4]));
      hc[r4] = (1.0f - zv) * nv + zv * hc[r4];
    }
    uint2 hp;
    hp.x = bf16_rn(hc[0]) | (bf16_rn(hc[1]) << 16);
    hp.y = bf16_rn(hc[2]) | (bf16_rn(hc[3]) << 16);
    *(uint2*)((char*)lds + (32 + ((i + 1) & 1)) * XS + hwb) = hp;
    __syncthreads();
  }
  int scan = sd * 64 + pg * 16 + p;
#pragma unroll
  for (int r4 = 0; r4 < 4; ++r4)
    hfin[(size_t)scan * 128 + c0 + r4] = hc[r4];
}

// ---- K4: out[b] = sigmoid(|lvec-rvec| . w_out + b_out)
__global__ __launch_bounds__(64) void k_out(const float* __restrict__ hfin,
                                            const float* __restrict__ w_out,
                                            const float* __restrict__ b_out,
                                            float* __restrict__ out) {
  int b = blockIdx.x, lane = threadIdx.x;
  float p = 0.f;
#pragma unroll
  for (int i = 0; i < 2; ++i) {
    int c = lane + i * 64;
    float l = hfin[(size_t)(0   + b) * 128 + c] + hfin[(size_t)(64  + b) * 128 + c];
    float r = hfin[(size_t)(128 + b) * 128 + c] + hfin[(size_t)(192 + b) * 128 + c];
    p += fabsf(l - r) * w_out[c];
  }
#pragma unroll
  for (int off = 32; off > 0; off >>= 1) p += __shfl_down(p, off);
  if (lane == 0) out[b] = sigm(p + b_out[0]);
}

extern "C" void kernel_launch(void* const* d_in, const int* in_sizes, int n_in,
                              void* d_out, int out_size, void* d_ws, size_t ws_size,
                              hipStream_t stream) {
  (void)in_sizes; (void)n_in; (void)out_size; (void)ws_size;
  const int*   tokens1 = (const int*)d_in[0];
  const int*   tokens2 = (const int*)d_in[2];
  const float* emb     = (const float*)d_in[4];
  const float* w_c     = (const float*)d_in[5];
  const float* b_c     = (const float*)d_in[6];
  const float* w_ih_f  = (const float*)d_in[7];
  const float* w_hh_f  = (const float*)d_in[8];
  const float* b_ih_f  = (const float*)d_in[9];
  const float* b_hh_f  = (const float*)d_in[10];
  const float* w_ih_b  = (const float*)d_in[11];
  const float* w_hh_b  = (const float*)d_in[12];
  const float* b_ih_b  = (const float*)d_in[13];
  const float* b_hh_b  = (const float*)d_in[14];
  const float* w_out   = (const float*)d_in[15];
  const float* b_out   = (const float*)d_in[16];
  float* ws = (float*)d_ws;
  unsigned short* projb = (unsigned short*)(ws + OFF_PROJ);
  float* seq    = ws + OFF_SEQ;
  float* hfin   = ws + OFF_HFIN;
  uint4* fragimg = (uint4*)(ws + OFF_FRAG);

  k_pack<<<96, 256, 0, stream>>>(w_ih_f, w_ih_b, w_hh_f, w_hh_b, fragimg);
  k_proj<<<(VSZ + 127) / 128, 512, 0, stream>>>(emb, w_c, b_c, projb);
  k_tree<<<dim3(TPS / 4, 2), 512, 0, stream>>>(tokens1, tokens2, projb, seq);
  k_scan<<<16, 512, 0, stream>>>(seq, fragimg, b_ih_f, b_ih_b, b_hh_f, b_hh_b, hfin);
  k_out<<<64, 64, 0, stream>>>(hfin, w_out, b_out, (float*)d_out);
}